// Round 25
// baseline (634.349 us; speedup 1.0000x reference)
//
#include <hip/hip_runtime.h>

#define NROWS 32768   // B*T = 16*2048
#define DIM 256
#define KCODES 1024
#define NLEV 4
#define CAP 64
#define MARGIN 8e-3f

typedef short short8v __attribute__((ext_vector_type(8)));
typedef float f32x4v  __attribute__((ext_vector_type(4)));

// bf16 round-to-nearest-even
static __device__ __forceinline__ unsigned short f2bf(float f) {
  unsigned u = __float_as_uint(f);
  unsigned lsb = (u >> 16) & 1u;
  u += 0x7fffu + lsb;
  return (unsigned short)(u >> 16);
}

// Packed fragment layout (per 16-row/16-code tile of 256 dims = 4096 shorts):
//   pak[tile][ks*512 + kb*128 + r8*8 + j] = elem(row = tile*16 + r8,
//                                               k = ks*32 + kb*8 + j)
// Wave reads short8v at pak + tile*4096 + ks*512 + lane*8 -> contiguous 1 KB.

// ============ codebook squared norms (unchanged, verified) ============
__global__ __launch_bounds__(256) void k_bnorm(const float* __restrict__ cb,
                                               float* __restrict__ bv) {
  int r = blockIdx.x * blockDim.x + threadIdx.x;
  if (r >= NLEV * KCODES) return;
  const float4* p = reinterpret_cast<const float4*>(cb + (size_t)r * DIM);
  float s0 = 0.f, s1 = 0.f, s2 = 0.f, s3 = 0.f;
  for (int g = 0; g < DIM / 4; ++g) {
    float4 v = p[g];
    s0 += v.x * v.x; s1 += v.y * v.y; s2 += v.z * v.z; s3 += v.w * v.w;
  }
  bv[r] = (s0 + s1) + (s2 + s3);
}

// ============ codebook -> bf16, PACKED fragment layout (verified r15) ============
__global__ __launch_bounds__(256) void k_csplit(const float* __restrict__ cb,
                                                unsigned short* __restrict__ chi) {
  const int tid = threadIdx.x;
  const int cr = blockIdx.x * 16 + (tid >> 4);
  const int l16 = tid & 15;
  const float4* p = reinterpret_cast<const float4*>(cb + (size_t)cr * DIM + l16 * 16);
  unsigned w[8];
  #pragma unroll
  for (int j = 0; j < 4; ++j) {
    float4 v = p[j];
    w[2 * j + 0] = (unsigned)f2bf(v.x) | ((unsigned)f2bf(v.y) << 16);
    w[2 * j + 1] = (unsigned)f2bf(v.z) | ((unsigned)f2bf(v.w) << 16);
  }
  const int lvl_ = cr >> 10;
  const int c = cr & 1023;
  unsigned short* base = chi + (size_t)lvl_ * (KCODES * DIM) + (size_t)(c >> 4) * 4096;
  const int c8 = c & 15;
  const int ks = l16 >> 1;
  const int kb0 = (l16 & 1) * 2;
  *reinterpret_cast<uint4*>(base + ks * 512 + kb0 * 128 + c8 * 8) =
      make_uint4(w[0], w[1], w[2], w[3]);
  *reinterpret_cast<uint4*>(base + ks * 512 + (kb0 + 1) * 128 + c8 * 8) =
      make_uint4(w[4], w[5], w[6], w[7]);
}

// ============ x -> rowsq + rhi (PACKED, verified r15) ============
__global__ __launch_bounds__(256) void k_prep(const float* __restrict__ x,
                                              unsigned short* __restrict__ rhi,
                                              float* __restrict__ rowsq) {
  __shared__ float sred[256];
  const int tid = threadIdx.x;
  const int rr = tid >> 4;
  const int l16 = tid & 15;
  const int row = blockIdx.x * 16 + rr;
  const float4* p = reinterpret_cast<const float4*>(x + (size_t)row * DIM + l16 * 16);
  float e = 0.f;
  unsigned w[8];
  #pragma unroll
  for (int j = 0; j < 4; ++j) {
    float4 v = p[j];
    e += v.x * v.x + v.y * v.y + v.z * v.z + v.w * v.w;
    w[2 * j + 0] = (unsigned)f2bf(v.x) | ((unsigned)f2bf(v.y) << 16);
    w[2 * j + 1] = (unsigned)f2bf(v.z) | ((unsigned)f2bf(v.w) << 16);
  }
  unsigned short* base = rhi + (size_t)blockIdx.x * 4096;
  const int ks = l16 >> 1;
  const int kb0 = (l16 & 1) * 2;
  *reinterpret_cast<uint4*>(base + ks * 512 + kb0 * 128 + rr * 8) =
      make_uint4(w[0], w[1], w[2], w[3]);
  *reinterpret_cast<uint4*>(base + ks * 512 + (kb0 + 1) * 128 + rr * 8) =
      make_uint4(w[4], w[5], w[6], w[7]);
  sred[tid] = e;
  __syncthreads();
  if (tid < 16) {
    float s = 0.f;
    #pragma unroll
    for (int k = 0; k < 16; ++k) s += sred[tid * 16 + k];
    rowsq[blockIdx.x * 16 + tid] = s;
  }
}

// ============ MFMA bf16 screen: 128-row x 256-code blocks (4x less panel BW) ============
// 1024 blocks = 256 row-blocks (128 rows) x 4 code-quarters. Wave = 2 row-
// tiles x 8 code-tiles (acc[2][8]=64 AGPR, 10-load fenced pack, ~124 regs ->
// 2 blocks/CU; identical inner loop to the verified r23/r24 screen). Panel
// read per block: 128 KB (vs 512 KB) -> L2 broadcast traffic /4 (the r24
// bottleneck). Row-min is 256-code-QUARTER-local: wave pairs sharing rows
// combine their two 128-code mins in LDS; survivors vs quarter-min + MARGIN
// (r16/r18-validated: MARGIN >= 2*err guarantees the true argmin's quarter
// emits it; others emit supersets -> u64-min rescore unaffected). Slots via
// global atomicAdd on once-zeroed counts. Fragments bit-identical to r12-r24.
__global__ __launch_bounds__(512, 4) void k_screen(const unsigned short* __restrict__ rhi,
                                                   const unsigned short* __restrict__ chi_l,
                                                   const float* __restrict__ bv_l,
                                                   const float* __restrict__ rowsq,
                                                   unsigned* __restrict__ survq,
                                                   unsigned* __restrict__ counts_l) {
  __shared__ float minb[128][2];
  const int tid = threadIdx.x;
  const int lane = tid & 63;
  const int w = tid >> 6;
  const int rg = w >> 1;            // row group 0..3 (32 rows each)
  const int ch = w & 1;             // code half 0..1 (128 codes each)
  const int rb = blockIdx.x & 255;  // row block (128 rows)
  const int q = blockIdx.x >> 8;    // code quarter
  const int row0 = rb * 128 + rg * 32;
  const int c0 = q * 256 + ch * 128;
  const int ln = lane & 15;
  const int kb = lane >> 4;

  f32x4v acc[2][8];
  #pragma unroll
  for (int r = 0; r < 2; ++r)
    #pragma unroll
    for (int t = 0; t < 8; ++t) acc[r][t] = (f32x4v){0.f, 0.f, 0.f, 0.f};

  const unsigned short* pa = rhi + (size_t)(rb * 8 + rg * 2) * 4096 + lane * 8;
  const unsigned short* pb = chi_l + (size_t)(q * 16 + ch * 8) * 4096 + lane * 8;

  #pragma unroll 1
  for (int ks = 0; ks < 8; ++ks) {
    // ---- load pack: 2 A + 8 B fragments, all independent ----
    short8v a0 = *reinterpret_cast<const short8v*>(pa + ks * 512);
    short8v a1 = *reinterpret_cast<const short8v*>(pa + 4096 + ks * 512);
    short8v b0 = *reinterpret_cast<const short8v*>(pb + 0 * 4096 + ks * 512);
    short8v b1 = *reinterpret_cast<const short8v*>(pb + 1 * 4096 + ks * 512);
    short8v b2 = *reinterpret_cast<const short8v*>(pb + 2 * 4096 + ks * 512);
    short8v b3 = *reinterpret_cast<const short8v*>(pb + 3 * 4096 + ks * 512);
    short8v b4 = *reinterpret_cast<const short8v*>(pb + 4 * 4096 + ks * 512);
    short8v b5 = *reinterpret_cast<const short8v*>(pb + 5 * 4096 + ks * 512);
    short8v b6 = *reinterpret_cast<const short8v*>(pb + 6 * 4096 + ks * 512);
    short8v b7 = *reinterpret_cast<const short8v*>(pb + 7 * 4096 + ks * 512);
    __builtin_amdgcn_sched_barrier(0);  // loads above, MFMAs below
    acc[0][0] = __builtin_amdgcn_mfma_f32_16x16x32_bf16(a0, b0, acc[0][0], 0, 0, 0);
    acc[1][0] = __builtin_amdgcn_mfma_f32_16x16x32_bf16(a1, b0, acc[1][0], 0, 0, 0);
    acc[0][1] = __builtin_amdgcn_mfma_f32_16x16x32_bf16(a0, b1, acc[0][1], 0, 0, 0);
    acc[1][1] = __builtin_amdgcn_mfma_f32_16x16x32_bf16(a1, b1, acc[1][1], 0, 0, 0);
    acc[0][2] = __builtin_amdgcn_mfma_f32_16x16x32_bf16(a0, b2, acc[0][2], 0, 0, 0);
    acc[1][2] = __builtin_amdgcn_mfma_f32_16x16x32_bf16(a1, b2, acc[1][2], 0, 0, 0);
    acc[0][3] = __builtin_amdgcn_mfma_f32_16x16x32_bf16(a0, b3, acc[0][3], 0, 0, 0);
    acc[1][3] = __builtin_amdgcn_mfma_f32_16x16x32_bf16(a1, b3, acc[1][3], 0, 0, 0);
    acc[0][4] = __builtin_amdgcn_mfma_f32_16x16x32_bf16(a0, b4, acc[0][4], 0, 0, 0);
    acc[1][4] = __builtin_amdgcn_mfma_f32_16x16x32_bf16(a1, b4, acc[1][4], 0, 0, 0);
    acc[0][5] = __builtin_amdgcn_mfma_f32_16x16x32_bf16(a0, b5, acc[0][5], 0, 0, 0);
    acc[1][5] = __builtin_amdgcn_mfma_f32_16x16x32_bf16(a1, b5, acc[1][5], 0, 0, 0);
    acc[0][6] = __builtin_amdgcn_mfma_f32_16x16x32_bf16(a0, b6, acc[0][6], 0, 0, 0);
    acc[1][6] = __builtin_amdgcn_mfma_f32_16x16x32_bf16(a1, b6, acc[1][6], 0, 0, 0);
    acc[0][7] = __builtin_amdgcn_mfma_f32_16x16x32_bf16(a0, b7, acc[0][7], 0, 0, 0);
    acc[1][7] = __builtin_amdgcn_mfma_f32_16x16x32_bf16(a1, b7, acc[1][7], 0, 0, 0);
  }

  // per-row partial min over this wave's 128 codes
  float bvl[8];
  #pragma unroll
  for (int t = 0; t < 8; ++t) bvl[t] = bv_l[c0 + t * 16 + ln];
  float rq[2][4];
  #pragma unroll
  for (int r = 0; r < 2; ++r)
    #pragma unroll
    for (int g = 0; g < 4; ++g) rq[r][g] = rowsq[row0 + r * 16 + kb * 4 + g];

  #pragma unroll
  for (int r = 0; r < 2; ++r) {
    #pragma unroll
    for (int g = 0; g < 4; ++g) {
      float v = __builtin_inff();
      #pragma unroll
      for (int t = 0; t < 8; ++t) {
        float dd = (rq[r][g] + bvl[t]) - 2.0f * acc[r][t][g];
        v = fminf(v, dd);
      }
      #pragma unroll
      for (int m = 1; m < 16; m <<= 1) v = fminf(v, __shfl_xor(v, m));
      if (ln == 0) minb[rg * 32 + r * 16 + kb * 4 + g][ch] = v;
    }
  }
  __syncthreads();
  // survivor emission vs 256-code-quarter min + MARGIN (r16/r18 semantics)
  #pragma unroll
  for (int r = 0; r < 2; ++r) {
    #pragma unroll
    for (int g = 0; g < 4; ++g) {
      const int rowloc = rg * 32 + r * 16 + kb * 4 + g;
      const int row = rb * 128 + rowloc;
      const float thr = fminf(minb[rowloc][0], minb[rowloc][1]) + MARGIN;
      #pragma unroll
      for (int t = 0; t < 8; ++t) {
        float dd = (rq[r][g] + bvl[t]) - 2.0f * acc[r][t][g];
        if (dd <= thr) {
          unsigned slot = atomicAdd(&counts_l[row], 1u);
          if (slot < CAP)
            survq[(size_t)row * CAP + slot] = (unsigned)(c0 + t * 16 + ln);
        }
      }
    }
  }
}

// ============ lean exact rescore + residual update (verified r24) ============
__global__ __launch_bounds__(256) void k_exupd(const float* __restrict__ x,
                                               const float* __restrict__ cb,
                                               const float* __restrict__ bv,
                                               const float* __restrict__ rowsq,
                                               const unsigned* __restrict__ survq,
                                               const unsigned* __restrict__ counts,
                                               int* __restrict__ idxh,
                                               float* __restrict__ fidx,
                                               float* __restrict__ part,
                                               float* __restrict__ rowsq_o,
                                               unsigned short* __restrict__ rhi,
                                               int lvl) {
  __shared__ __align__(16) float rlds[16][260];
  __shared__ int idsh[16];
  __shared__ float sred[256];
  __shared__ float rsum[16];

  const int tid = threadIdx.x;
  const int rr = tid >> 4;
  const int l16 = tid & 15;
  const int row = blockIdx.x * 16 + rr;
  const size_t obase = (size_t)row * DIM + l16 * 16;
  const float* cb_l = cb + (size_t)lvl * KCODES * DIM;
  const float* bv_l = bv + lvl * KCODES;

  // ---- phase A: residual via verified fl chain; stage row in LDS ----
  float4 rj[4];
  {
    const float4* xp = reinterpret_cast<const float4*>(x + obase);
    #pragma unroll
    for (int j = 0; j < 4; ++j) rj[j] = xp[j];
    for (int p = 0; p < lvl; ++p) {
      const float4* qp = reinterpret_cast<const float4*>(
          cb + ((size_t)p * KCODES + idxh[p * NROWS + row]) * DIM + l16 * 16);
      #pragma unroll
      for (int j = 0; j < 4; ++j) {
        float4 q = qp[j];
        rj[j].x -= q.x; rj[j].y -= q.y; rj[j].z -= q.z; rj[j].w -= q.w;
      }
    }
    #pragma unroll
    for (int j = 0; j < 4; ++j)
      *reinterpret_cast<float4*>(&rlds[rr][l16 * 16 + 4 * j]) = rj[j];
  }
  __syncthreads();

  // ---- phase B: exact chains on survivors (verified) ----
  const float A = rowsq[row];
  const unsigned n = counts[row];
  unsigned long long best = ~0ull;

#define CHAIN(CODE)                                                            \
  {                                                                            \
    const float* cp2 = cb_l + (size_t)(CODE) * DIM;                            \
    float a0 = 0.f;                                                            \
    _Pragma("unroll 8")                                                        \
    for (int dv = 0; dv < DIM / 4; ++dv) {                                     \
      float4 rv = *reinterpret_cast<const float4*>(&rlds[rr][dv * 4]);         \
      float4 cv = *reinterpret_cast<const float4*>(cp2 + dv * 4);              \
      a0 = fmaf(rv.x, cv.x, a0); a0 = fmaf(rv.y, cv.y, a0);                    \
      a0 = fmaf(rv.z, cv.z, a0); a0 = fmaf(rv.w, cv.w, a0);                    \
    }                                                                          \
    float t = A + bv_l[(CODE)];   /* fl(A + B) */                              \
    float dd = t - 2.0f * a0;     /* one rounding (2*dot exact) */             \
    unsigned long long pk =                                                    \
        ((unsigned long long)__float_as_uint(dd) << 32) | (unsigned)(CODE);    \
    best = (pk < best) ? pk : best;                                            \
  }

  if (n <= CAP) {
    for (unsigned s = l16; s < n; s += 16) {
      unsigned code = survq[(size_t)row * CAP + s];
      CHAIN(code);
    }
  } else {
    for (unsigned c = l16; c < KCODES; c += 16) CHAIN(c);  // safety net
  }
#undef CHAIN

  #pragma unroll
  for (int m = 1; m < 16; m <<= 1) {
    unsigned long long o = __shfl_xor(best, m);
    best = (o < best) ? o : best;
  }
  if (l16 == 0) {
    const int id = (int)(best & 0xffffffffull);
    idxh[lvl * NROWS + row] = id;
    fidx[lvl * NROWS + row] = (float)id;
    idsh[rr] = id;
  }
  __syncthreads();

  // ---- phase C (lean): nn, loss partial, next rhi, rowsq ----
  const int id = idsh[rr];
  const float4* cpc = reinterpret_cast<const float4*>(
      cb_l + (size_t)id * DIM + l16 * 16);
  float nn[16];
  float e = 0.f;
  #pragma unroll
  for (int j = 0; j < 4; ++j) {
    float4 c = cpc[j];
    float n0 = rj[j].x - c.x, n1 = rj[j].y - c.y;
    float n2 = rj[j].z - c.z, n3 = rj[j].w - c.w;
    nn[4 * j + 0] = n0; nn[4 * j + 1] = n1; nn[4 * j + 2] = n2; nn[4 * j + 3] = n3;
    e += (n0 * n0 + n1 * n1) + (n2 * n2 + n3 * n3);
  }

  if (lvl < 3) {
    unsigned w[8];
    #pragma unroll
    for (int k = 0; k < 8; ++k)
      w[k] = (unsigned)f2bf(nn[2 * k]) | ((unsigned)f2bf(nn[2 * k + 1]) << 16);
    unsigned short* base = rhi + (size_t)blockIdx.x * 4096;
    const int ks = l16 >> 1;
    const int kb0 = (l16 & 1) * 2;
    *reinterpret_cast<uint4*>(base + ks * 512 + kb0 * 128 + rr * 8) =
        make_uint4(w[0], w[1], w[2], w[3]);
    *reinterpret_cast<uint4*>(base + ks * 512 + (kb0 + 1) * 128 + rr * 8) =
        make_uint4(w[4], w[5], w[6], w[7]);
  }

  sred[tid] = e;
  __syncthreads();
  if (tid < 16) {
    float s = 0.f;
    #pragma unroll
    for (int k = 0; k < 16; ++k) s += sred[tid * 16 + k];
    rsum[tid] = s;
    if (lvl < 3) rowsq_o[blockIdx.x * 16 + tid] = s;
  }
  __syncthreads();
  if (tid == 0) {
    float p = 0.f;
    #pragma unroll
    for (int k = 0; k < 16; ++k) p += rsum[k];
    part[blockIdx.x] = p;
  }
}

// ============ final STE: out = x + (((c0+c1)+c2)+c3 - x) (verified r24) ============
__global__ __launch_bounds__(256) void k_ste(const float* __restrict__ x,
                                             const float* __restrict__ cb,
                                             const int* __restrict__ idxh,
                                             float* __restrict__ out) {
  const int tid = threadIdx.x;
  const int row = blockIdx.x * 16 + (tid >> 4);
  const int l16 = tid & 15;
  const size_t obase = (size_t)row * DIM + l16 * 16;
  const float4* c0p = reinterpret_cast<const float4*>(
      cb + ((size_t)0 * KCODES + idxh[0 * NROWS + row]) * DIM + l16 * 16);
  const float4* c1p = reinterpret_cast<const float4*>(
      cb + ((size_t)1 * KCODES + idxh[1 * NROWS + row]) * DIM + l16 * 16);
  const float4* c2p = reinterpret_cast<const float4*>(
      cb + ((size_t)2 * KCODES + idxh[2 * NROWS + row]) * DIM + l16 * 16);
  const float4* c3p = reinterpret_cast<const float4*>(
      cb + ((size_t)3 * KCODES + idxh[3 * NROWS + row]) * DIM + l16 * 16);
  const float4* xp = reinterpret_cast<const float4*>(x + obase);
  float4* op = reinterpret_cast<float4*>(out + obase);
  #pragma unroll
  for (int j = 0; j < 4; ++j) {
    float4 c0 = c0p[j], c1 = c1p[j], c2 = c2p[j], c3 = c3p[j], xv = xp[j];
    float4 tv;
    tv.x = c0.x; tv.y = c0.y; tv.z = c0.z; tv.w = c0.w;
    tv.x += c1.x; tv.y += c1.y; tv.z += c1.z; tv.w += c1.w;
    tv.x += c2.x; tv.y += c2.y; tv.z += c2.z; tv.w += c2.w;
    tv.x += c3.x; tv.y += c3.y; tv.z += c3.z; tv.w += c3.w;
    tv.x = xv.x + (tv.x - xv.x); tv.y = xv.y + (tv.y - xv.y);
    tv.z = xv.z + (tv.z - xv.z); tv.w = xv.w + (tv.w - xv.w);
    op[j] = tv;
  }
}

// ============ loss finalize (unchanged) ============
__global__ __launch_bounds__(256) void k_loss(const float* __restrict__ part,
                                              float* __restrict__ out) {
  __shared__ float s[256];
  const int tid = threadIdx.x;
  float means[4];
  for (int l = 0; l < 4; ++l) {
    float sum = 0.f;
    for (int i = tid; i < 2048; i += 256) sum += part[l * 2048 + i];
    s[tid] = sum;
    __syncthreads();
    for (int st = 128; st > 0; st >>= 1) {
      if (tid < st) s[tid] += s[tid + st];
      __syncthreads();
    }
    means[l] = s[0] * (1.0f / 8388608.0f);
    __syncthreads();
  }
  if (tid == 0) {
    float t = ((means[0] + means[1]) + means[2]) + means[3];
    float loss = t * 0.25f;
    out[0] = loss;
    out[1] = loss;
  }
}

extern "C" void kernel_launch(void* const* d_in, const int* in_sizes, int n_in,
                              void* d_out, int out_size, void* d_ws, size_t ws_size,
                              hipStream_t stream) {
  const float* x  = (const float*)d_in[0];
  const float* cb = (const float*)d_in[1];
  float* out = (float*)d_out;
  float* ws  = (float*)d_ws;

  // ws layout (float units)
  unsigned short* rhi = (unsigned short*)ws;                         // 4194304 f
  unsigned short* chi = (unsigned short*)(ws + 4194304);             // 524288 f
  unsigned* survq   = (unsigned*)(ws + 4194304 + 524288);            // 2097152 f
  unsigned* counts4 = (unsigned*)(ws + 4194304 + 524288 + 2097152);  // 131072 f (4 levels)
  int* idxh = (int*)(ws + 4194304 + 524288 + 2097152 + 131072);      // 131072 f
  float* bv    = ws + 4194304 + 524288 + 2097152 + 131072 + 131072;  // 4096
  float* rowsq = bv + 4096;                                          // 32768
  float* part  = rowsq + 32768;                                      // 8192

  float* lossout = out + 8388608;
  float* fidx    = out + 8388610;

  hipMemsetAsync(counts4, 0, (size_t)NLEV * NROWS * sizeof(unsigned), stream);
  k_bnorm<<<16, 256, 0, stream>>>(cb, bv);
  k_csplit<<<256, 256, 0, stream>>>(cb, chi);
  k_prep<<<2048, 256, 0, stream>>>(x, rhi, rowsq);

  for (int l = 0; l < NLEV; ++l) {
    unsigned* counts_l = counts4 + (size_t)l * NROWS;
    k_screen<<<1024, 512, 0, stream>>>(rhi, chi + (size_t)l * KCODES * DIM,
                                       bv + l * KCODES, rowsq, survq, counts_l);
    k_exupd<<<2048, 256, 0, stream>>>(x, cb, bv, rowsq, survq, counts_l,
                                      idxh, fidx, part + l * 2048,
                                      rowsq, rhi, l);
  }

  k_ste<<<2048, 256, 0, stream>>>(x, cb, idxh, out);
  k_loss<<<1, 256, 0, stream>>>(part, lossout);
}

// Round 26
// 348.347 us; speedup vs baseline: 1.8210x; 1.8210x over previous
//
#include <hip/hip_runtime.h>

#define NROWS 32768   // B*T = 16*2048
#define DIM 256
#define KCODES 1024
#define NLEV 4
#define CAP 64
#define MARGIN 8e-3f

typedef short short8v __attribute__((ext_vector_type(8)));
typedef float f32x4v  __attribute__((ext_vector_type(4)));

// bf16 round-to-nearest-even
static __device__ __forceinline__ unsigned short f2bf(float f) {
  unsigned u = __float_as_uint(f);
  unsigned lsb = (u >> 16) & 1u;
  u += 0x7fffu + lsb;
  return (unsigned short)(u >> 16);
}

// Packed fragment layout (per 16-row/16-code tile of 256 dims = 4096 shorts):
//   pak[tile][ks*512 + kb*128 + r8*8 + j] = elem(row = tile*16 + r8,
//                                               k = ks*32 + kb*8 + j)
// Wave reads short8v at pak + tile*4096 + ks*512 + lane*8 -> contiguous 1 KB.

// ============ codebook squared norms (unchanged, verified) ============
__global__ __launch_bounds__(256) void k_bnorm(const float* __restrict__ cb,
                                               float* __restrict__ bv) {
  int r = blockIdx.x * blockDim.x + threadIdx.x;
  if (r >= NLEV * KCODES) return;
  const float4* p = reinterpret_cast<const float4*>(cb + (size_t)r * DIM);
  float s0 = 0.f, s1 = 0.f, s2 = 0.f, s3 = 0.f;
  for (int g = 0; g < DIM / 4; ++g) {
    float4 v = p[g];
    s0 += v.x * v.x; s1 += v.y * v.y; s2 += v.z * v.z; s3 += v.w * v.w;
  }
  bv[r] = (s0 + s1) + (s2 + s3);
}

// ============ codebook -> bf16, PACKED fragment layout (verified r15) ============
__global__ __launch_bounds__(256) void k_csplit(const float* __restrict__ cb,
                                                unsigned short* __restrict__ chi) {
  const int tid = threadIdx.x;
  const int cr = blockIdx.x * 16 + (tid >> 4);
  const int l16 = tid & 15;
  const float4* p = reinterpret_cast<const float4*>(cb + (size_t)cr * DIM + l16 * 16);
  unsigned w[8];
  #pragma unroll
  for (int j = 0; j < 4; ++j) {
    float4 v = p[j];
    w[2 * j + 0] = (unsigned)f2bf(v.x) | ((unsigned)f2bf(v.y) << 16);
    w[2 * j + 1] = (unsigned)f2bf(v.z) | ((unsigned)f2bf(v.w) << 16);
  }
  const int lvl_ = cr >> 10;
  const int c = cr & 1023;
  unsigned short* base = chi + (size_t)lvl_ * (KCODES * DIM) + (size_t)(c >> 4) * 4096;
  const int c8 = c & 15;
  const int ks = l16 >> 1;
  const int kb0 = (l16 & 1) * 2;
  *reinterpret_cast<uint4*>(base + ks * 512 + kb0 * 128 + c8 * 8) =
      make_uint4(w[0], w[1], w[2], w[3]);
  *reinterpret_cast<uint4*>(base + ks * 512 + (kb0 + 1) * 128 + c8 * 8) =
      make_uint4(w[4], w[5], w[6], w[7]);
}

// ============ x -> rowsq + rhi (PACKED, verified r15) ============
__global__ __launch_bounds__(256) void k_prep(const float* __restrict__ x,
                                              unsigned short* __restrict__ rhi,
                                              float* __restrict__ rowsq) {
  __shared__ float sred[256];
  const int tid = threadIdx.x;
  const int rr = tid >> 4;
  const int l16 = tid & 15;
  const int row = blockIdx.x * 16 + rr;
  const float4* p = reinterpret_cast<const float4*>(x + (size_t)row * DIM + l16 * 16);
  float e = 0.f;
  unsigned w[8];
  #pragma unroll
  for (int j = 0; j < 4; ++j) {
    float4 v = p[j];
    e += v.x * v.x + v.y * v.y + v.z * v.z + v.w * v.w;
    w[2 * j + 0] = (unsigned)f2bf(v.x) | ((unsigned)f2bf(v.y) << 16);
    w[2 * j + 1] = (unsigned)f2bf(v.z) | ((unsigned)f2bf(v.w) << 16);
  }
  unsigned short* base = rhi + (size_t)blockIdx.x * 4096;
  const int ks = l16 >> 1;
  const int kb0 = (l16 & 1) * 2;
  *reinterpret_cast<uint4*>(base + ks * 512 + kb0 * 128 + rr * 8) =
      make_uint4(w[0], w[1], w[2], w[3]);
  *reinterpret_cast<uint4*>(base + ks * 512 + (kb0 + 1) * 128 + rr * 8) =
      make_uint4(w[4], w[5], w[6], w[7]);
  sred[tid] = e;
  __syncthreads();
  if (tid < 16) {
    float s = 0.f;
    #pragma unroll
    for (int k = 0; k < 16; ++k) s += sred[tid * 16 + k];
    rowsq[blockIdx.x * 16 + tid] = s;
  }
}

// ============ MFMA bf16 screen: 1-deep fenced pack, 2 blocks/CU (verified r23/r24) ============
__global__ __launch_bounds__(512, 4) void k_screen(const unsigned short* __restrict__ rhi,
                                                   const unsigned short* __restrict__ chi_l,
                                                   const float* __restrict__ bv_l,
                                                   const float* __restrict__ rowsq,
                                                   unsigned* __restrict__ survq,
                                                   unsigned* __restrict__ counts) {
  __shared__ float minb[32][8];
  __shared__ float rowminf[32];
  __shared__ unsigned cnt[32];
  const int tid = threadIdx.x;
  const int lane = tid & 63;
  const int w = tid >> 6;          // wave 0..7 -> codes w*128..+127
  const int rb = blockIdx.x;       // 32-row block
  const int row0 = rb * 32;
  const int c0 = w * 128;
  const int ln = lane & 15;
  const int kb = lane >> 4;

  f32x4v acc[2][8];
  #pragma unroll
  for (int r = 0; r < 2; ++r)
    #pragma unroll
    for (int t = 0; t < 8; ++t) acc[r][t] = (f32x4v){0.f, 0.f, 0.f, 0.f};

  const unsigned short* pa = rhi + (size_t)(rb * 2) * 4096 + lane * 8;
  const unsigned short* pb = chi_l + (size_t)(w * 8) * 4096 + lane * 8;

  #pragma unroll 1
  for (int ks = 0; ks < 8; ++ks) {
    short8v a0 = *reinterpret_cast<const short8v*>(pa + ks * 512);
    short8v a1 = *reinterpret_cast<const short8v*>(pa + 4096 + ks * 512);
    short8v b0 = *reinterpret_cast<const short8v*>(pb + 0 * 4096 + ks * 512);
    short8v b1 = *reinterpret_cast<const short8v*>(pb + 1 * 4096 + ks * 512);
    short8v b2 = *reinterpret_cast<const short8v*>(pb + 2 * 4096 + ks * 512);
    short8v b3 = *reinterpret_cast<const short8v*>(pb + 3 * 4096 + ks * 512);
    short8v b4 = *reinterpret_cast<const short8v*>(pb + 4 * 4096 + ks * 512);
    short8v b5 = *reinterpret_cast<const short8v*>(pb + 5 * 4096 + ks * 512);
    short8v b6 = *reinterpret_cast<const short8v*>(pb + 6 * 4096 + ks * 512);
    short8v b7 = *reinterpret_cast<const short8v*>(pb + 7 * 4096 + ks * 512);
    __builtin_amdgcn_sched_barrier(0);  // loads above, MFMAs below
    acc[0][0] = __builtin_amdgcn_mfma_f32_16x16x32_bf16(a0, b0, acc[0][0], 0, 0, 0);
    acc[1][0] = __builtin_amdgcn_mfma_f32_16x16x32_bf16(a1, b0, acc[1][0], 0, 0, 0);
    acc[0][1] = __builtin_amdgcn_mfma_f32_16x16x32_bf16(a0, b1, acc[0][1], 0, 0, 0);
    acc[1][1] = __builtin_amdgcn_mfma_f32_16x16x32_bf16(a1, b1, acc[1][1], 0, 0, 0);
    acc[0][2] = __builtin_amdgcn_mfma_f32_16x16x32_bf16(a0, b2, acc[0][2], 0, 0, 0);
    acc[1][2] = __builtin_amdgcn_mfma_f32_16x16x32_bf16(a1, b2, acc[1][2], 0, 0, 0);
    acc[0][3] = __builtin_amdgcn_mfma_f32_16x16x32_bf16(a0, b3, acc[0][3], 0, 0, 0);
    acc[1][3] = __builtin_amdgcn_mfma_f32_16x16x32_bf16(a1, b3, acc[1][3], 0, 0, 0);
    acc[0][4] = __builtin_amdgcn_mfma_f32_16x16x32_bf16(a0, b4, acc[0][4], 0, 0, 0);
    acc[1][4] = __builtin_amdgcn_mfma_f32_16x16x32_bf16(a1, b4, acc[1][4], 0, 0, 0);
    acc[0][5] = __builtin_amdgcn_mfma_f32_16x16x32_bf16(a0, b5, acc[0][5], 0, 0, 0);
    acc[1][5] = __builtin_amdgcn_mfma_f32_16x16x32_bf16(a1, b5, acc[1][5], 0, 0, 0);
    acc[0][6] = __builtin_amdgcn_mfma_f32_16x16x32_bf16(a0, b6, acc[0][6], 0, 0, 0);
    acc[1][6] = __builtin_amdgcn_mfma_f32_16x16x32_bf16(a1, b6, acc[1][6], 0, 0, 0);
    acc[0][7] = __builtin_amdgcn_mfma_f32_16x16x32_bf16(a0, b7, acc[0][7], 0, 0, 0);
    acc[1][7] = __builtin_amdgcn_mfma_f32_16x16x32_bf16(a1, b7, acc[1][7], 0, 0, 0);
  }

  // per-row partial min over this wave's 128 codes
  float bvl[8];
  #pragma unroll
  for (int t = 0; t < 8; ++t) bvl[t] = bv_l[c0 + t * 16 + ln];
  float rq[2][4];
  #pragma unroll
  for (int r = 0; r < 2; ++r)
    #pragma unroll
    for (int g = 0; g < 4; ++g) rq[r][g] = rowsq[row0 + r * 16 + kb * 4 + g];

  #pragma unroll
  for (int r = 0; r < 2; ++r) {
    #pragma unroll
    for (int g = 0; g < 4; ++g) {
      float v = __builtin_inff();
      #pragma unroll
      for (int t = 0; t < 8; ++t) {
        float dd = (rq[r][g] + bvl[t]) - 2.0f * acc[r][t][g];
        v = fminf(v, dd);
      }
      #pragma unroll
      for (int m = 1; m < 16; m <<= 1) v = fminf(v, __shfl_xor(v, m));
      if (ln == 0) minb[r * 16 + kb * 4 + g][w] = v;
    }
  }
  __syncthreads();
  if (tid < 32) {
    float v = minb[tid][0];
    #pragma unroll
    for (int k = 1; k < 8; ++k) v = fminf(v, minb[tid][k]);
    rowminf[tid] = v;   // TRUE screen min over all 1024 codes
    cnt[tid] = 0;
  }
  __syncthreads();
  // survivor emission vs global screen min + MARGIN (r15/r20-r24 semantics)
  #pragma unroll
  for (int r = 0; r < 2; ++r) {
    #pragma unroll
    for (int g = 0; g < 4; ++g) {
      const int rowloc = r * 16 + kb * 4 + g;
      const float thr = rowminf[rowloc] + MARGIN;
      #pragma unroll
      for (int t = 0; t < 8; ++t) {
        float dd = (rq[r][g] + bvl[t]) - 2.0f * acc[r][t][g];
        if (dd <= thr) {
          unsigned slot = atomicAdd(&cnt[rowloc], 1u);
          if (slot < CAP)
            survq[(size_t)(row0 + rowloc) * CAP + slot] =
                (unsigned)(c0 + t * 16 + ln);
        }
      }
    }
  }
  __syncthreads();
  if (tid < 32) counts[row0 + tid] = cnt[tid];
}

// ============ lean exact rescore + residual update (verified r24) ============
__global__ __launch_bounds__(256) void k_exupd(const float* __restrict__ x,
                                               const float* __restrict__ cb,
                                               const float* __restrict__ bv,
                                               const float* __restrict__ rowsq,
                                               const unsigned* __restrict__ survq,
                                               const unsigned* __restrict__ counts,
                                               int* __restrict__ idxh,
                                               float* __restrict__ fidx,
                                               float* __restrict__ part,
                                               float* __restrict__ rowsq_o,
                                               unsigned short* __restrict__ rhi,
                                               int lvl) {
  __shared__ __align__(16) float rlds[16][260];
  __shared__ int idsh[16];
  __shared__ float sred[256];
  __shared__ float rsum[16];

  const int tid = threadIdx.x;
  const int rr = tid >> 4;
  const int l16 = tid & 15;
  const int row = blockIdx.x * 16 + rr;
  const size_t obase = (size_t)row * DIM + l16 * 16;
  const float* cb_l = cb + (size_t)lvl * KCODES * DIM;
  const float* bv_l = bv + lvl * KCODES;

  // ---- phase A: residual via verified fl chain; stage row in LDS ----
  float4 rj[4];
  {
    const float4* xp = reinterpret_cast<const float4*>(x + obase);
    #pragma unroll
    for (int j = 0; j < 4; ++j) rj[j] = xp[j];
    for (int p = 0; p < lvl; ++p) {
      const float4* qp = reinterpret_cast<const float4*>(
          cb + ((size_t)p * KCODES + idxh[p * NROWS + row]) * DIM + l16 * 16);
      #pragma unroll
      for (int j = 0; j < 4; ++j) {
        float4 q = qp[j];
        rj[j].x -= q.x; rj[j].y -= q.y; rj[j].z -= q.z; rj[j].w -= q.w;
      }
    }
    #pragma unroll
    for (int j = 0; j < 4; ++j)
      *reinterpret_cast<float4*>(&rlds[rr][l16 * 16 + 4 * j]) = rj[j];
  }
  __syncthreads();

  // ---- phase B: exact chains on survivors (verified) ----
  const float A = rowsq[row];
  const unsigned n = counts[row];
  unsigned long long best = ~0ull;

#define CHAIN(CODE)                                                            \
  {                                                                            \
    const float* cp2 = cb_l + (size_t)(CODE) * DIM;                            \
    float a0 = 0.f;                                                            \
    _Pragma("unroll 8")                                                        \
    for (int dv = 0; dv < DIM / 4; ++dv) {                                     \
      float4 rv = *reinterpret_cast<const float4*>(&rlds[rr][dv * 4]);         \
      float4 cv = *reinterpret_cast<const float4*>(cp2 + dv * 4);              \
      a0 = fmaf(rv.x, cv.x, a0); a0 = fmaf(rv.y, cv.y, a0);                    \
      a0 = fmaf(rv.z, cv.z, a0); a0 = fmaf(rv.w, cv.w, a0);                    \
    }                                                                          \
    float t = A + bv_l[(CODE)];   /* fl(A + B) */                              \
    float dd = t - 2.0f * a0;     /* one rounding (2*dot exact) */             \
    unsigned long long pk =                                                    \
        ((unsigned long long)__float_as_uint(dd) << 32) | (unsigned)(CODE);    \
    best = (pk < best) ? pk : best;                                            \
  }

  if (n <= CAP) {
    for (unsigned s = l16; s < n; s += 16) {
      unsigned code = survq[(size_t)row * CAP + s];
      CHAIN(code);
    }
  } else {
    for (unsigned c = l16; c < KCODES; c += 16) CHAIN(c);  // safety net
  }
#undef CHAIN

  #pragma unroll
  for (int m = 1; m < 16; m <<= 1) {
    unsigned long long o = __shfl_xor(best, m);
    best = (o < best) ? o : best;
  }
  if (l16 == 0) {
    const int id = (int)(best & 0xffffffffull);
    idxh[lvl * NROWS + row] = id;
    fidx[lvl * NROWS + row] = (float)id;
    idsh[rr] = id;
  }
  __syncthreads();

  // ---- phase C (lean): nn, loss partial, next rhi, rowsq ----
  const int id = idsh[rr];
  const float4* cpc = reinterpret_cast<const float4*>(
      cb_l + (size_t)id * DIM + l16 * 16);
  float nn[16];
  float e = 0.f;
  #pragma unroll
  for (int j = 0; j < 4; ++j) {
    float4 c = cpc[j];
    float n0 = rj[j].x - c.x, n1 = rj[j].y - c.y;
    float n2 = rj[j].z - c.z, n3 = rj[j].w - c.w;
    nn[4 * j + 0] = n0; nn[4 * j + 1] = n1; nn[4 * j + 2] = n2; nn[4 * j + 3] = n3;
    e += (n0 * n0 + n1 * n1) + (n2 * n2 + n3 * n3);
  }

  if (lvl < 3) {
    unsigned w[8];
    #pragma unroll
    for (int k = 0; k < 8; ++k)
      w[k] = (unsigned)f2bf(nn[2 * k]) | ((unsigned)f2bf(nn[2 * k + 1]) << 16);
    unsigned short* base = rhi + (size_t)blockIdx.x * 4096;
    const int ks = l16 >> 1;
    const int kb0 = (l16 & 1) * 2;
    *reinterpret_cast<uint4*>(base + ks * 512 + kb0 * 128 + rr * 8) =
        make_uint4(w[0], w[1], w[2], w[3]);
    *reinterpret_cast<uint4*>(base + ks * 512 + (kb0 + 1) * 128 + rr * 8) =
        make_uint4(w[4], w[5], w[6], w[7]);
  }

  sred[tid] = e;
  __syncthreads();
  if (tid < 16) {
    float s = 0.f;
    #pragma unroll
    for (int k = 0; k < 16; ++k) s += sred[tid * 16 + k];
    rsum[tid] = s;
    if (lvl < 3) rowsq_o[blockIdx.x * 16 + tid] = s;
  }
  __syncthreads();
  if (tid == 0) {
    float p = 0.f;
    #pragma unroll
    for (int k = 0; k < 16; ++k) p += rsum[k];
    part[blockIdx.x] = p;
  }
}

// ============ final STE: out = x + (((c0+c1)+c2)+c3 - x) (verified r24) ============
__global__ __launch_bounds__(256) void k_ste(const float* __restrict__ x,
                                             const float* __restrict__ cb,
                                             const int* __restrict__ idxh,
                                             float* __restrict__ out) {
  const int tid = threadIdx.x;
  const int row = blockIdx.x * 16 + (tid >> 4);
  const int l16 = tid & 15;
  const size_t obase = (size_t)row * DIM + l16 * 16;
  const float4* c0p = reinterpret_cast<const float4*>(
      cb + ((size_t)0 * KCODES + idxh[0 * NROWS + row]) * DIM + l16 * 16);
  const float4* c1p = reinterpret_cast<const float4*>(
      cb + ((size_t)1 * KCODES + idxh[1 * NROWS + row]) * DIM + l16 * 16);
  const float4* c2p = reinterpret_cast<const float4*>(
      cb + ((size_t)2 * KCODES + idxh[2 * NROWS + row]) * DIM + l16 * 16);
  const float4* c3p = reinterpret_cast<const float4*>(
      cb + ((size_t)3 * KCODES + idxh[3 * NROWS + row]) * DIM + l16 * 16);
  const float4* xp = reinterpret_cast<const float4*>(x + obase);
  float4* op = reinterpret_cast<float4*>(out + obase);
  #pragma unroll
  for (int j = 0; j < 4; ++j) {
    float4 c0 = c0p[j], c1 = c1p[j], c2 = c2p[j], c3 = c3p[j], xv = xp[j];
    float4 tv;
    tv.x = c0.x; tv.y = c0.y; tv.z = c0.z; tv.w = c0.w;
    tv.x += c1.x; tv.y += c1.y; tv.z += c1.z; tv.w += c1.w;
    tv.x += c2.x; tv.y += c2.y; tv.z += c2.z; tv.w += c2.w;
    tv.x += c3.x; tv.y += c3.y; tv.z += c3.z; tv.w += c3.w;
    tv.x = xv.x + (tv.x - xv.x); tv.y = xv.y + (tv.y - xv.y);
    tv.z = xv.z + (tv.z - xv.z); tv.w = xv.w + (tv.w - xv.w);
    op[j] = tv;
  }
}

// ============ loss finalize (unchanged) ============
__global__ __launch_bounds__(256) void k_loss(const float* __restrict__ part,
                                              float* __restrict__ out) {
  __shared__ float s[256];
  const int tid = threadIdx.x;
  float means[4];
  for (int l = 0; l < 4; ++l) {
    float sum = 0.f;
    for (int i = tid; i < 2048; i += 256) sum += part[l * 2048 + i];
    s[tid] = sum;
    __syncthreads();
    for (int st = 128; st > 0; st >>= 1) {
      if (tid < st) s[tid] += s[tid + st];
      __syncthreads();
    }
    means[l] = s[0] * (1.0f / 8388608.0f);
    __syncthreads();
  }
  if (tid == 0) {
    float t = ((means[0] + means[1]) + means[2]) + means[3];
    float loss = t * 0.25f;
    out[0] = loss;
    out[1] = loss;
  }
}

extern "C" void kernel_launch(void* const* d_in, const int* in_sizes, int n_in,
                              void* d_out, int out_size, void* d_ws, size_t ws_size,
                              hipStream_t stream) {
  const float* x  = (const float*)d_in[0];
  const float* cb = (const float*)d_in[1];
  float* out = (float*)d_out;
  float* ws  = (float*)d_ws;

  // ws layout (float units)
  unsigned short* rhi = (unsigned short*)ws;                         // 4194304 f
  unsigned short* chi = (unsigned short*)(ws + 4194304);             // 524288 f
  unsigned* survq  = (unsigned*)(ws + 4194304 + 524288);             // 2097152 f
  unsigned* counts = (unsigned*)(ws + 4194304 + 524288 + 2097152);   // 32768 f
  int* idxh = (int*)(ws + 4194304 + 524288 + 2097152 + 131072);      // 131072 f
  float* bv    = ws + 4194304 + 524288 + 2097152 + 131072 + 131072;  // 4096
  float* rowsq = bv + 4096;                                          // 32768
  float* part  = rowsq + 32768;                                      // 8192

  float* lossout = out + 8388608;
  float* fidx    = out + 8388610;

  k_bnorm<<<16, 256, 0, stream>>>(cb, bv);
  k_csplit<<<256, 256, 0, stream>>>(cb, chi);
  k_prep<<<2048, 256, 0, stream>>>(x, rhi, rowsq);

  for (int l = 0; l < NLEV; ++l) {
    k_screen<<<1024, 512, 0, stream>>>(rhi, chi + (size_t)l * KCODES * DIM,
                                       bv + l * KCODES, rowsq, survq, counts);
    k_exupd<<<2048, 256, 0, stream>>>(x, cb, bv, rowsq, survq, counts,
                                      idxh, fidx, part + l * 2048,
                                      rowsq, rhi, l);
  }

  k_ste<<<2048, 256, 0, stream>>>(x, cb, idxh, out);
  k_loss<<<1, 256, 0, stream>>>(part, lossout);
}